// Round 8
// baseline (330.555 us; speedup 1.0000x reference)
//
#include <hip/hip_runtime.h>

// Batched Viterbi decode: B=1024, S=512, T=64.
// R10 (resubmit; round-7 failure was container-infra, as in round 1): R9 +
// register-pin of the transitions row. Evidence: VGPR_Count=76 while the
// forward live set should be >=130 -> the compiler REMATERIALIZES t[64] from
// global memory inside the step loop (~16 L1-hit dwordx4/step/wave, 4
// waves/CU) -- this explains R5/R9's ~800 cyc/step vs ~250 issue, R6's
// regression (T8 remat + added serial DPP chain), and R8's collapse. Fix:
// asm volatile("" : "+v"(t[p])) after the load -- volatile asm outputs cannot
// be re-executed, forcing t[] to stay VGPR-resident and preventing load
// sinking. No semantic change; forward math + backtrace byte-identical to the
// verified R9. Equality backtrace: bptr_s[n*] = first p with
// (vv_{s-1}[p]+feat[s-1][p]) + T[n*,p] == vv_s[n*]; adds replay forward adds
// bitwise, fmax returns an operand bitwise, ballot compares by VALUE, so
// ctz(ballot) == jnp first-index argmax on any input. R4 fallback kept.

#define B_ 1024
#define S_ 512
#define T_ 64
#define NEGV -10000.0f

// ---------------- R10 fast path ----------------
__global__ __launch_bounds__(64, 1) void viterbi_fwd_bt(
    const float* __restrict__ feats,   // [B, S, T]
    const float* __restrict__ trans,   // [T, T]
    float* __restrict__ out,           // [B + B*S]
    float* __restrict__ vv)            // workspace [B, S, T]: pre-feat max per step
{
    __shared__ float T_lds[T_ * T_];              // 16 KB transitions copy (row-major)
    __shared__ __align__(16) float fvbuf[2][T_];  // parity-double-buffered fv

    const int b = blockIdx.x;
    const int lane = threadIdx.x;      // forward: lane = next tag; backtrace: lane = prev tag

    // stage transitions into LDS for backtrace row reads (coalesced float4)
    {
        const float4* src = reinterpret_cast<const float4*>(trans);
        float4* dst = reinterpret_cast<float4*>(T_lds);
#pragma unroll
        for (int i = 0; i < 16; ++i) dst[i * 64 + lane] = src[i * 64 + lane];
    }

    // transitions row for next = lane
    float t[T_];
#pragma unroll
    for (int p = 0; p < T_; p += 4) {
        const float4 v = *reinterpret_cast<const float4*>(trans + lane * T_ + p);
        t[p] = v.x; t[p + 1] = v.y; t[p + 2] = v.z; t[p + 3] = v.w;
    }
    // PIN: force t[] VGPR-resident; volatile asm output cannot be remat'd,
    // so the compiler cannot re-load trans inside the step loop.
#pragma unroll
    for (int p = 0; p < T_; ++p)
        asm volatile("" : "+v"(t[p]));

    const float tend = trans[(T_ - 1) * T_ + lane];   // transitions[END][lane]

    float fv = (lane == T_ - 2) ? 0.0f : NEGV;        // START = T-2
    fvbuf[0][lane] = fv;

    const float* fb = feats + (size_t)b * S_ * T_ + lane;
    float* vw = vv + (size_t)b * S_ * T_ + lane;

    // feat prefetch ring: 4 steps ahead
    float fc[4], fn[4];
#pragma unroll
    for (int k = 0; k < 4; ++k) fc[k] = fb[(size_t)k * T_];

#pragma unroll 1
    for (int s4 = 0; s4 < S_ / 4; ++s4) {
#pragma unroll
        for (int k = 0; k < 4; ++k) {
            int sp = 4 * s4 + 4 + k;
            sp = (sp < S_) ? sp : (S_ - 1);
            fn[k] = fb[(size_t)sp * T_];
        }

        float mv[4];                      // buffered step-maxes (stores issued after body)
#pragma unroll
        for (int u = 0; u < 4; ++u) {
            const int s = 4 * s4 + u;
            const int rs = s & 1;
            // 64 candidates: add + fmax tree (no argmax tracking)
            float gm[16];
#pragma unroll
            for (int j = 0; j < 16; ++j) {
                const float4 v = *reinterpret_cast<const float4*>(&fvbuf[rs][4 * j]);
                const float c0 = v.x + t[4 * j];
                const float c1 = v.y + t[4 * j + 1];
                const float c2 = v.z + t[4 * j + 2];
                const float c3 = v.w + t[4 * j + 3];
                gm[j] = fmaxf(fmaxf(c0, c1), fmaxf(c2, c3));
            }
#pragma unroll
            for (int off = 8; off >= 1; off >>= 1)
#pragma unroll
                for (int j = 0; j < off; ++j) gm[j] = fmaxf(gm[j], gm[j + off]);
            const float maxv = gm[0];

            mv[u] = maxv;                 // defer the global store (off the chain)
            fv = maxv + fc[u];
            fvbuf[rs ^ 1][lane] = fv;
        }

        // issue the 4 deferred vw stores (same addresses/values as per-step R5)
#pragma unroll
        for (int u = 0; u < 4; ++u)
            vw[(size_t)(4 * s4 + u) * T_] = mv[u];

#pragma unroll
        for (int k = 0; k < 4; ++k) fc[k] = fn[k];
    }

    // terminal: max/argmax over tags (butterfly, first-index ties)
    float v = fv + tend;
    int i = lane;
#pragma unroll
    for (int off = 1; off < 64; off <<= 1) {
        const float vo = __shfl_xor(v, off);
        const int io = __shfl_xor(i, off);
        const bool take = (vo > v) || ((vo == v) && (io < i));
        v = take ? vo : v;
        i = take ? io : i;
    }
    int ncur = __builtin_amdgcn_readfirstlane(i);
    if (lane == 0) out[b] = v;

    // ---- backtrace: equality search, 1 ballot per step (verbatim R5) ----
    asm volatile("s_waitcnt vmcnt(0)" ::: "memory");  // vv stores visible to our loads

    float A = vw[(size_t)(S_ - 1) * T_];              // vv_511 vector (lane p holds [p])
    float vvR[8], ffR[8];
#pragma unroll
    for (int k = 0; k < 8; ++k) {
        const int s = (S_ - 1) - k;
        vvR[k] = vw[(size_t)(s - 1) * T_];
        ffR[k] = fb[(size_t)(s - 1) * T_];
    }

    float emitv = 0.0f;
    float* outp = out + B_ + (size_t)b * S_;

#pragma unroll 1
    for (int c = 7; c >= 0; --c) {
#pragma unroll 1
        for (int g = 7; g >= 0; --g) {
            const int base = 64 * c + 8 * g;
#pragma unroll
            for (int kk = 0; kk < 8; ++kk) {
                const int s = base + 7 - kk;
                emitv = (lane == (s & 63)) ? (float)ncur : emitv;
                if (s > 0) {
                    const float target = __int_as_float(
                        __builtin_amdgcn_readlane(__float_as_int(A), ncur));
                    const float trow = T_lds[(ncur << 6) + lane];
                    const float cand = (vvR[kk] + ffR[kk]) + trow;
                    const unsigned long long m = __ballot(cand == target);
                    ncur = ((int)__builtin_ctzll(m)) & 63;   // first p == first-index argmax
                    A = vvR[kk];
                    const int sp = (s >= 9) ? (s - 9) : 0;
                    vvR[kk] = vw[(size_t)sp * T_];
                    ffR[kk] = fb[(size_t)sp * T_];
                }
            }
        }
        outp[64 * c + lane] = emitv;   // coalesced 256B store per chunk
    }
}

// ---------------- R4 fallback (verified; used when workspace too small) ----------------
__global__ __launch_bounds__(64, 1) void viterbi_kernel(
    const float* __restrict__ feats,
    const float* __restrict__ trans,
    float* __restrict__ out)
{
    __shared__ unsigned int bp[S_ / 4][T_];
    __shared__ __align__(16) float fvbuf[2][T_];

    const int b = blockIdx.x;
    const int lane = threadIdx.x;

    float t[T_];
#pragma unroll
    for (int p = 0; p < T_; p += 4) {
        const float4 v = *reinterpret_cast<const float4*>(trans + lane * T_ + p);
        t[p] = v.x; t[p + 1] = v.y; t[p + 2] = v.z; t[p + 3] = v.w;
    }
    const float tend = trans[(T_ - 1) * T_ + lane];

    float fv = (lane == T_ - 2) ? 0.0f : NEGV;
    fvbuf[0][lane] = fv;

    const float* fb = feats + (size_t)b * S_ * T_ + lane;

    float fc[4], fn[4];
#pragma unroll
    for (int k = 0; k < 4; ++k) fc[k] = fb[(size_t)k * T_];

#pragma unroll 1
    for (int s4 = 0; s4 < S_ / 4; ++s4) {
#pragma unroll
        for (int k = 0; k < 4; ++k) {
            int sp = 4 * s4 + 4 + k;
            sp = (sp < S_) ? sp : (S_ - 1);
            fn[k] = fb[(size_t)sp * T_];
        }

        unsigned int pack = 0;
#pragma unroll
        for (int u = 0; u < 4; ++u) {
            const int s = 4 * s4 + u;
            const int rs = s & 1;

            float fvl[T_];
#pragma unroll
            for (int j = 0; j < 16; ++j) {
                const float4 v = *reinterpret_cast<const float4*>(&fvbuf[rs][4 * j]);
                fvl[4 * j] = v.x; fvl[4 * j + 1] = v.y;
                fvl[4 * j + 2] = v.z; fvl[4 * j + 3] = v.w;
            }

            float bv[4]; int bi[4];
#pragma unroll
            for (int g = 0; g < 4; ++g) {
                float bestv = fvl[16 * g] + t[16 * g];
                int besti = 16 * g;
#pragma unroll
                for (int q = 1; q < 16; ++q) {
                    const int p = 16 * g + q;
                    const float c = fvl[p] + t[p];
                    const bool gt = c > bestv;
                    besti = gt ? p : besti;
                    bestv = gt ? c : bestv;
                }
                bv[g] = bestv; bi[g] = besti;
            }
            float BV = bv[0]; int BI = bi[0];
#pragma unroll
            for (int g = 1; g < 4; ++g) {
                const bool gt = bv[g] > BV;
                BI = gt ? bi[g] : BI;
                BV = gt ? bv[g] : BV;
            }

            fv = BV + fc[u];
            fvbuf[rs ^ 1][lane] = fv;
            pack |= ((unsigned int)BI) << (8 * u);
        }
        bp[s4][lane] = pack;

#pragma unroll
        for (int k = 0; k < 4; ++k) fc[k] = fn[k];
    }

    float v = fv + tend;
    int i = lane;
#pragma unroll
    for (int off = 1; off < 64; off <<= 1) {
        const float vo = __shfl_xor(v, off);
        const int io = __shfl_xor(i, off);
        const bool take = (vo > v) || ((vo == v) && (io < i));
        v = take ? vo : v;
        i = take ? io : i;
    }
    int tcur = __builtin_amdgcn_readfirstlane(i);
    if (lane == 0) out[b] = v;

    float* outp = out + B_ + (size_t)b * S_;
#pragma unroll 1
    for (int c = 7; c >= 0; --c) {
        unsigned int wd[16];
#pragma unroll
        for (int j = 0; j < 16; ++j)
            wd[j] = bp[16 * c + j][lane];

        int emit = 0;
#pragma unroll
        for (int k = 63; k >= 0; --k) {
            emit = (lane == k) ? tcur : emit;
            const int word = __builtin_amdgcn_readlane((int)wd[k >> 2], tcur);
            tcur = (word >> (8 * (k & 3))) & 0xff;
        }
        outp[64 * c + lane] = (float)emit;
    }
}

extern "C" void kernel_launch(void* const* d_in, const int* in_sizes, int n_in,
                              void* d_out, int out_size, void* d_ws, size_t ws_size,
                              hipStream_t stream) {
    const float* feats = (const float*)d_in[0];   // [B*S*T] f32
    const float* trans = (const float*)d_in[1];   // [T*T] f32
    float* out = (float*)d_out;                   // [B + B*S] f32

    const size_t need = (size_t)B_ * S_ * T_ * sizeof(float);  // 128 MiB
    if (d_ws != nullptr && ws_size >= need) {
        viterbi_fwd_bt<<<dim3(B_), dim3(T_), 0, stream>>>(feats, trans, out, (float*)d_ws);
    } else {
        viterbi_kernel<<<dim3(B_), dim3(T_), 0, stream>>>(feats, trans, out);
    }
}